// Round 8
// baseline (360.334 us; speedup 1.0000x reference)
//
#include <hip/hip_runtime.h>

#define TT 2048
#define NV 1000
#define LOG2E 1.4426950408889634f

// ---- XLA/Eigen rational tanh — epilogue head only (off critical path).
__device__ __forceinline__ float tanh_fast(float x) {
    const float L = 7.90531110763549805f;
    x = __builtin_amdgcn_fmed3f(x, -L, L);
    float x2 = x * x;
    float p = -2.76076847742355e-16f;
    p = __builtin_fmaf(p, x2, 2.00018790482477e-13f);
    p = __builtin_fmaf(p, x2, -8.60467152213735e-11f);
    p = __builtin_fmaf(p, x2, 5.12229709037114e-08f);
    p = __builtin_fmaf(p, x2, 1.48572235717979e-05f);
    p = __builtin_fmaf(p, x2, 6.37261928875436e-04f);
    p = __builtin_fmaf(p, x2, 4.89352455891786e-03f);
    float q = 1.19825839466702e-06f;
    q = __builtin_fmaf(q, x2, 1.18534705686654e-04f);
    q = __builtin_fmaf(q, x2, 2.26843463243900e-03f);
    q = __builtin_fmaf(q, x2, 4.89352518554385e-03f);
    float r = __builtin_amdgcn_rcpf(q);
    return (x * p) * r;
}

// DPP cross-lane.
template <int CTRL>
__device__ __forceinline__ float dppf(float x) {
    return __int_as_float(__builtin_amdgcn_update_dpp(
        0, __float_as_int(x), CTRL, 0xF, 0xF, true));
}
#define DPP_XOR1 0xB1   // quad_perm [1,0,3,2]
#define DPP_XOR2 0x4E   // quad_perm [2,3,0,1]
#define DPP_XOR3 0x1B   // quad_perm [3,2,1,0]
#define DPP_ROR4 0x124  // row_ror:4 == xor4 on period-8 data (validated R3-R10)
#define DPP_HMIR 0x141  // row_half_mirror == xor7 within 8-lane half
#define DPP_ROR8 0x128  // row_ror:8 == xor8 within 16-row (exact bit-3 flip)

// Cross-16 "dual broadcast" via gfx950 v_permlane16_swap_b32 (VALU pipe — no
// lgkm interaction, unlike R12's ds_swizzle). With both inputs = a:
//   av[L] = a[L & ~16]   (low-16 value of the 32-pair)
//   bv[L] = a[L |  16]   (high-16 value of the 32-pair)
typedef unsigned u32x2 __attribute__((ext_vector_type(2)));
__device__ __forceinline__ void xswap16(float a, float& av, float& bv) {
#if __has_builtin(__builtin_amdgcn_permlane16_swap)
    u32x2 r = __builtin_amdgcn_permlane16_swap(
        __float_as_int(a), __float_as_int(a), false, false);
    av = __int_as_float(r[0]);
    bv = __int_as_float(r[1]);
#else
    float x = a, y = a;
    asm("v_permlane16_swap_b32 %0, %1" : "+v"(x), "+v"(y));
    av = x; bv = y;
#endif
}

// R17 (re-run; previous attempt died to container infra, no data).
// 32 lanes/row, 2 waves/SIMD, all cross-lane on the VALU pipe.
// Lane L (0..31): j = L&7 (h-index), gate = L>>3 in order i,f,g,o -> the
// gate row in W_ih/W_hh/biases is simply grow = L. Each lane owns ONE gate.
//   - dot h_{j^m}: identical DPP set to the validated 16-lane kernels
//     (QP1/2/3 on hn, HMIR multi-use mm, QP3/2/1 on mm) — j is in lane
//     bits {0,1,2}, no cross-16 needed.
//   - i<->g and f<->o pair across bit4: ONE permlane16_swap gives
//     av=a[i-side], bv=a[g-side] per 32-pair: P=av*bv = k*sig(i)*tanh(g)
//     at i/g lanes; F=av=sig(f), O=bv=sig(o) at f/o lanes (no cndmask).
//   - P -> c lanes and h broadcast: exact ROR8 (bit-3 flip).
// Gate math & scaled-domain c-path = R14 verbatim (value-identical per
// gate): sigma lanes a=r; g lanes a=fma(2k,r,-k), k=-2log2e; cs=fma(F,cs,Pr);
// ec=exp2(cs); rc=rcp(1+ec); h=fma(2O,rc,-O). absmax-0.0-validated class.
// 512 thr x 256 blk = 2048 waves = 2/SIMD (TAB 125 KB -> 1 block/CU).
extern "C" __global__ void __launch_bounds__(512, 2)
lstm_fused(const int* __restrict__ x, const float* __restrict__ emb,
           const float* __restrict__ W_ih, const float* __restrict__ W_hh,
           const float* __restrict__ b_ih, const float* __restrict__ b_hh,
           const float* __restrict__ W_cls, const float* __restrict__ b_cls,
           float* __restrict__ out)
{
    extern __shared__ float TAB[];  // [1000][32] floats, 128 B rows

    const int tid = threadIdx.x;
    const int L   = tid & 31;       // lane within 32-lane row-group
    const int grp = tid >> 5;       // 16 row-groups per block
    const int j   = L & 7;
    const int qi  = L >> 3;         // 0=i 1=f 2=g 3=o (PyTorch gate order)
    const bool isG  = (qi == 2);
    const bool isHi = (qi & 1);     // b3: f/o lanes hold the real c,h
    const float sc  = isG ? (-2.0f * LOG2E) : -LOG2E;  // gate prescale
    // a = fma(Ax, r, Bx): sigma lanes -> r (exact); g -> k*tanh(g), k=-2log2e
    const float Ax = isG ? (-4.0f * LOG2E) : 1.0f;
    const float Bx = isG ? ( 2.0f * LOG2E) : 0.0f;

    // ---- phase 1: build TAB (one gate pre-activation per lane; grow = L) ----
    {
        float w[8];
        #pragma unroll
        for (int k = 0; k < 8; ++k) w[k] = W_ih[L * 8 + k];
        const float bb = b_ih[L] + b_hh[L];
        for (int v = grp; v < NV; v += 16) {
            const float4 e0 = *(const float4*)(emb + v * 8);
            const float4 e1 = *(const float4*)(emb + v * 8 + 4);
            float d = bb + e0.x*w[0] + e0.y*w[1] + e0.z*w[2] + e0.w*w[3]
                         + e1.x*w[4] + e1.y*w[5] + e1.z*w[6] + e1.w*w[7];
            TAB[v * 32 + L] = sc * d;
        }
    }
    __syncthreads();

    // ---- recurrence ----
    const int b = blockIdx.x * 16 + grp;
    const int* __restrict__ xrow = x + (size_t)b * TT;
    const char* __restrict__ TABl = (const char*)TAB + L * 4;

    // xor-ordered W_hh: term m multiplies h_{j^m} (R3-R16 validated pairing)
    float w[8];
    #pragma unroll
    for (int m = 0; m < 8; ++m)
        w[m] = sc * W_hh[L * 8 + (j ^ m)];

    float cs = 0.0f;   // scaled cell state cs = -2log2e*c (real at f/o lanes)
    float hn = 0.0f;   // h_{L&7}, period-8 across the 32-lane group

    int4 iA = *(const int4*)(xrow);
    int4 iB = *(const int4*)(xrow + 4);
    float xg0 = *(const float*)(TABl + (iA.x << 7));  // depth-2 prefetch
    float xg1 = *(const float*)(TABl + (iA.y << 7));

    // Dot chain order == R6/R9/R14: uA: m0,m2,m4,m6; uB: m1,m3,m5,m7.
#define STEP(XG, NIDX) do {                                                    \
        float mm = dppf<DPP_HMIR>(hn);           /* h_{j^7}, multi-use */      \
        float uA = __builtin_fmaf(hn, w[0], XG);                               \
        float uB = dppf<DPP_XOR1>(hn) * w[1];                                  \
        uA = __builtin_fmaf(dppf<DPP_XOR2>(hn), w[2], uA);                     \
        uB = __builtin_fmaf(dppf<DPP_XOR3>(hn), w[3], uB);                     \
        uA = __builtin_fmaf(dppf<DPP_XOR3>(mm), w[4], uA);                     \
        uB = __builtin_fmaf(dppf<DPP_XOR2>(mm), w[5], uB);                     \
        uA = __builtin_fmaf(dppf<DPP_XOR1>(mm), w[6], uA);                     \
        uB = __builtin_fmaf(mm, w[7], uB);                                     \
        float u = uA + uB;   /* -log2e*pre (sigma) / -2log2e*pre_g (g) */      \
        XG = *(const float*)(TABl + ((NIDX) << 7));   /* prefetch t+2 */       \
        float e = __builtin_amdgcn_exp2f(u);                                   \
        float r = __builtin_amdgcn_rcpf(1.0f + e);                             \
        float a = __builtin_fmaf(Ax, r, Bx);     /* sig / k*tanh(g) */         \
        float av, bv;                                                          \
        xswap16(a, av, bv);   /* av=a[L&~16] bv=a[L|16] (VALU permlane) */     \
        float P  = av * bv;                      /* k*sig(i)*tg at i/g */      \
        float Pr = dppf<DPP_ROR8>(P);            /* -> f/o lanes */            \
        float twoO = bv + bv;                    /* O=bv at f/o lanes */       \
        cs = __builtin_fmaf(av, cs, Pr);         /* F=av at f/o lanes */       \
        float ec = __builtin_amdgcn_exp2f(cs);   /* e^{-2c}, inf-safe */       \
        float rc = __builtin_amdgcn_rcpf(1.0f + ec);                           \
        float h  = __builtin_fmaf(twoO, rc, -bv);  /* O*tanh(c) */             \
        float hq = dppf<DPP_ROR8>(h);            /* broadcast to i/g lanes */  \
        hn = isHi ? h : hq;                                                    \
    } while (0)

    for (int t = 0; t < TT; t += 4) {
        const int nb = (t + 8 < TT) ? (t / 4 + 2) : 0;  // clamp tail prefetch
        int4 iN = *(const int4*)(xrow + nb * 4);
        STEP(xg0, iA.z);
        STEP(xg1, iA.w);
        STEP(xg0, iB.x);
        STEP(xg1, iB.y);
        iA = iB; iB = iN;
    }
#undef STEP

    // ---- head: out[b] = 0.5 + 0.5*tanh(0.5*(h.W_cls + b_cls)) ----
    // Lane L==0 of each group: hn=h_0; same summation order as R2-R16.
    {
        float v1 = dppf<DPP_XOR1>(hn);
        float v2 = dppf<DPP_XOR2>(hn);
        float v3 = dppf<DPP_XOR3>(hn);
        float v4 = dppf<DPP_ROR4>(hn);   // h_4 (period-8, direction-immune)
        float v5 = dppf<DPP_XOR1>(v4);
        float v6 = dppf<DPP_XOR2>(v4);
        float v7 = dppf<DPP_XOR3>(v4);
        if (L == 0) {
            float z = b_cls[0]
                + hn * W_cls[0] + v1 * W_cls[1] + v2 * W_cls[2] + v3 * W_cls[3]
                + v4 * W_cls[4] + v5 * W_cls[5] + v6 * W_cls[6] + v7 * W_cls[7];
            out[b] = __builtin_fmaf(0.5f, tanh_fast(0.5f * z), 0.5f);
        }
    }
}

extern "C" void kernel_launch(void* const* d_in, const int* in_sizes, int n_in,
                              void* d_out, int out_size, void* d_ws, size_t ws_size,
                              hipStream_t stream)
{
    (void)in_sizes; (void)n_in; (void)d_ws; (void)ws_size; (void)out_size;
    const int*   x     = (const int*)  d_in[0];
    const float* emb   = (const float*)d_in[1];
    const float* W_ih  = (const float*)d_in[2];
    const float* W_hh  = (const float*)d_in[3];
    const float* b_ih  = (const float*)d_in[4];
    const float* b_hh  = (const float*)d_in[5];
    const float* W_cls = (const float*)d_in[6];
    const float* b_cls = (const float*)d_in[7];
    float* out = (float*)d_out;

    const int lds_bytes = NV * 32 * 4;  // 128000 <= 163840 (gfx950 opt-in)
    hipFuncSetAttribute((const void*)lstm_fused,
                        hipFuncAttributeMaxDynamicSharedMemorySize, lds_bytes);

    lstm_fused<<<dim3(256), dim3(512), lds_bytes, stream>>>(
        x, emb, W_ih, W_hh, b_ih, b_hh, W_cls, b_cls, out);
}

// Round 9
// 353.074 us; speedup vs baseline: 1.0206x; 1.0206x over previous
//
#include <hip/hip_runtime.h>

#define TT 2048
#define NV 1000
#define LOG2E 1.4426950408889634f

typedef float f32x2 __attribute__((ext_vector_type(2)));

// ---- XLA/Eigen rational tanh — epilogue head only (off critical path).
__device__ __forceinline__ float tanh_fast(float x) {
    const float L = 7.90531110763549805f;
    x = __builtin_amdgcn_fmed3f(x, -L, L);
    float x2 = x * x;
    float p = -2.76076847742355e-16f;
    p = __builtin_fmaf(p, x2, 2.00018790482477e-13f);
    p = __builtin_fmaf(p, x2, -8.60467152213735e-11f);
    p = __builtin_fmaf(p, x2, 5.12229709037114e-08f);
    p = __builtin_fmaf(p, x2, 1.48572235717979e-05f);
    p = __builtin_fmaf(p, x2, 6.37261928875436e-04f);
    p = __builtin_fmaf(p, x2, 4.89352455891786e-03f);
    float q = 1.19825839466702e-06f;
    q = __builtin_fmaf(q, x2, 1.18534705686654e-04f);
    q = __builtin_fmaf(q, x2, 2.26843463243900e-03f);
    q = __builtin_fmaf(q, x2, 4.89352518554385e-03f);
    float r = __builtin_amdgcn_rcpf(q);
    return (x * p) * r;
}

// DPP cross-lane.
template <int CTRL>
__device__ __forceinline__ float dppf(float x) {
    return __int_as_float(__builtin_amdgcn_update_dpp(
        0, __float_as_int(x), CTRL, 0xF, 0xF, true));
}
#define DPP_XOR1 0xB1   // quad_perm [1,0,3,2]
#define DPP_XOR2 0x4E   // quad_perm [2,3,0,1]
#define DPP_XOR3 0x1B   // quad_perm [3,2,1,0]
#define DPP_HMIR 0x141  // row_half_mirror: l -> 7-l within 8-lane half == j^7

// pk helper: per-component ops bitwise-identical to scalar forms.
__device__ __forceinline__ f32x2 pkfma(f32x2 a, float b, f32x2 c) {
    return __builtin_elementwise_fma(a, (f32x2){b, b}, c);
}

// R18: P=8 layout — 8 lanes per row, each lane owns ALL FOUR gates of one
// (row, j). Attacks the serial chain (R14 is chain-bound: 258 cyc/step,
// 172 busy): the i*g product, F*c and O*tanh(c) are now IN-LANE, removing
// both on-chain ROR8 hops and both cndmasks (~20 cyc off the chain), and
// trans drop 12 -> 10 per 8 rows. Dot = 4 gates x 8 terms as 16 pk_fma
// sharing the SAME validated 7-DPP shuffle set (j in lane bits 0-2; HMIR
// gives j^7 within the 8-lane half; m4..m6 via XOR3/2/1 of HMIR).
// Per-gate math is value-identical to R14 (absmax-0.0 class):
//   sigma: r = rcp(1 + exp2(-log2e*pre));  g: k*tanh = fma(-4log2e, r, 2log2e)
//   cs = fma(sig_f, cs, sig_i * ktanh_g)   [k = -2log2e folded, R14 scheme]
//   ec = exp2(cs); rc = rcp(1+ec); hn = fma(2*sig_o, rc, -sig_o)
// 512 waves on 1024 SIMDs (half idle — irrelevant, chain-bound).
// 256 blocks x 128 thr: every CU gets 1 block (2 waves, own LDS).
// TAB = [1000][8 j][4 gate] floats = 128 KB (same budget, float4/lane reads).
extern "C" __global__ void __launch_bounds__(128, 1)
lstm_fused(const int* __restrict__ x, const float* __restrict__ emb,
           const float* __restrict__ W_ih, const float* __restrict__ W_hh,
           const float* __restrict__ b_ih, const float* __restrict__ b_hh,
           const float* __restrict__ W_cls, const float* __restrict__ b_cls,
           float* __restrict__ out)
{
    extern __shared__ float TAB[];  // [1000][32] floats, 128 B rows

    const int tid = threadIdx.x;
    const int j   = tid & 7;        // h-index within the 8-lane group
    const int grp = tid >> 3;       // 16 row-groups per 128-thr block

    // ---- phase 1: build TAB: role (j2, q) = one gate scalar per lane ----
    {
        const int L2 = tid & 31;
        const int j2 = L2 >> 2;
        const int q  = L2 & 3;               // 0=i 1=f 2=g 3=o
        const int row = q * 8 + j2;
        const float sc = (q == 2) ? (-2.0f * LOG2E) : -LOG2E;
        float w[8];
        #pragma unroll
        for (int k = 0; k < 8; ++k) w[k] = W_ih[row * 8 + k];
        const float bb = b_ih[row] + b_hh[row];
        for (int v = tid >> 5; v < NV; v += 4) {
            const float4 e0 = *(const float4*)(emb + v * 8);
            const float4 e1 = *(const float4*)(emb + v * 8 + 4);
            float d = bb + e0.x*w[0] + e0.y*w[1] + e0.z*w[2] + e0.w*w[3]
                         + e1.x*w[4] + e1.y*w[5] + e1.z*w[6] + e1.w*w[7];
            TAB[v * 32 + j2 * 4 + q] = sc * d;
        }
    }
    __syncthreads();

    // ---- recurrence ----
    const int b = blockIdx.x * 16 + grp;
    const int* __restrict__ xrow = x + (size_t)b * TT;
    const char* __restrict__ TABl = (const char*)TAB + j * 16;  // lane base

    // xor-ordered W_hh, all 4 gate rows per lane (term m pairs with h_{j^m}).
    // Gate rows: i=j, f=8+j, g=16+j, o=24+j.
    f32x2 wif[8], wgo[8];
    #pragma unroll
    for (int m = 0; m < 8; ++m) {
        const int c = j ^ m;
        wif[m].x = -LOG2E          * W_hh[(j     ) * 8 + c];
        wif[m].y = -LOG2E          * W_hh[(8  + j) * 8 + c];
        wgo[m].x = (-2.0f * LOG2E) * W_hh[(16 + j) * 8 + c];
        wgo[m].y = -LOG2E          * W_hh[(24 + j) * 8 + c];
    }

    float cs = 0.0f;   // scaled cell state: cs = -2log2e * c (R14 scheme)
    float hn = 0.0f;   // h_j, period-8 across the wave

    int4 iA = *(const int4*)(xrow);
    int4 iB = *(const int4*)(xrow + 4);
    float4 xg0 = *(const float4*)(TABl + (iA.x << 7));  // depth-2 prefetch
    float4 xg1 = *(const float4*)(TABl + (iA.y << 7));

    // Dot order per gate == R6/R9/R14: uA: m0,m2,m4,m6; uB: m1,m3,m5,m7.
#define STEP(XG, NIDX) do {                                                    \
        float mm = dppf<DPP_HMIR>(hn);           /* h_{j^7}, multi-use */      \
        f32x2 uAif = pkfma(wif[0], hn, (f32x2){XG.x, XG.y});                   \
        f32x2 uAgo = pkfma(wgo[0], hn, (f32x2){XG.z, XG.w});                   \
        float h1 = dppf<DPP_XOR1>(hn);                                         \
        f32x2 uBif = wif[1] * (f32x2){h1, h1};                                 \
        f32x2 uBgo = wgo[1] * (f32x2){h1, h1};                                 \
        float h2 = dppf<DPP_XOR2>(hn);                                         \
        uAif = pkfma(wif[2], h2, uAif);                                        \
        uAgo = pkfma(wgo[2], h2, uAgo);                                        \
        float h3 = dppf<DPP_XOR3>(hn);                                         \
        uBif = pkfma(wif[3], h3, uBif);                                        \
        uBgo = pkfma(wgo[3], h3, uBgo);                                        \
        float h4 = dppf<DPP_XOR3>(mm);           /* h_{j^4} */                 \
        uAif = pkfma(wif[4], h4, uAif);                                        \
        uAgo = pkfma(wgo[4], h4, uAgo);                                        \
        float h5 = dppf<DPP_XOR2>(mm);           /* h_{j^5} */                 \
        uBif = pkfma(wif[5], h5, uBif);                                        \
        uBgo = pkfma(wgo[5], h5, uBgo);                                        \
        float h6 = dppf<DPP_XOR1>(mm);           /* h_{j^6} */                 \
        uAif = pkfma(wif[6], h6, uAif);                                        \
        uAgo = pkfma(wgo[6], h6, uAgo);                                        \
        uBif = pkfma(wif[7], mm, uBif);                                        \
        uBgo = pkfma(wgo[7], mm, uBgo);                                        \
        f32x2 uif = uAif + uBif;                                               \
        f32x2 ugo = uAgo + uBgo;                                               \
        XG = *(const float4*)(TABl + ((NIDX) << 7));   /* prefetch t+2 */      \
        float ei = __builtin_amdgcn_exp2f(uif.x);                              \
        float ef = __builtin_amdgcn_exp2f(uif.y);                              \
        float eg = __builtin_amdgcn_exp2f(ugo.x);                              \
        float eo = __builtin_amdgcn_exp2f(ugo.y);                              \
        float ri = __builtin_amdgcn_rcpf(1.0f + ei);   /* sig(i) */            \
        float rf = __builtin_amdgcn_rcpf(1.0f + ef);   /* sig(f) */            \
        float rg = __builtin_amdgcn_rcpf(1.0f + eg);                           \
        float ro = __builtin_amdgcn_rcpf(1.0f + eo);   /* sig(o) */            \
        float tgk = __builtin_fmaf(-4.0f * LOG2E, rg, 2.0f * LOG2E);           \
        float IG  = ri * tgk;                    /* k*sig(i)*tanh(g) */        \
        cs = __builtin_fmaf(rf, cs, IG);         /* cs = k*c */                \
        float ec = __builtin_amdgcn_exp2f(cs);   /* e^{-2c}, inf-safe */       \
        float rc = __builtin_amdgcn_rcpf(1.0f + ec);                           \
        float twoO = ro + ro;                                                  \
        hn = __builtin_fmaf(twoO, rc, -ro);      /* O * tanh(c) */             \
    } while (0)

    for (int t = 0; t < TT; t += 4) {
        const int nb = (t + 8 < TT) ? (t / 4 + 2) : 0;  // clamp tail prefetch
        int4 iN = *(const int4*)(xrow + nb * 4);
        STEP(xg0, iA.z);
        STEP(xg1, iA.w);
        STEP(xg0, iB.x);
        STEP(xg1, iB.y);
        iA = iB; iB = iN;
    }
#undef STEP

    // ---- head: out[b] = 0.5 + 0.5*tanh(0.5*(h.W_cls + b_cls)) ----
    // Lane j==0: hn=h_0; v_m = h_m, summation order identical to R2-R17.
    {
        float mm = dppf<DPP_HMIR>(hn);           // h_7 at lane 0
        float v1 = dppf<DPP_XOR1>(hn);
        float v2 = dppf<DPP_XOR2>(hn);
        float v3 = dppf<DPP_XOR3>(hn);
        float v4 = dppf<DPP_XOR3>(mm);           // h_4
        float v5 = dppf<DPP_XOR2>(mm);           // h_5
        float v6 = dppf<DPP_XOR1>(mm);           // h_6
        if (j == 0) {
            float z = b_cls[0]
                + hn * W_cls[0] + v1 * W_cls[1] + v2 * W_cls[2] + v3 * W_cls[3]
                + v4 * W_cls[4] + v5 * W_cls[5] + v6 * W_cls[6] + mm * W_cls[7];
            out[b] = __builtin_fmaf(0.5f, tanh_fast(0.5f * z), 0.5f);
        }
    }
}

extern "C" void kernel_launch(void* const* d_in, const int* in_sizes, int n_in,
                              void* d_out, int out_size, void* d_ws, size_t ws_size,
                              hipStream_t stream)
{
    (void)in_sizes; (void)n_in; (void)d_ws; (void)ws_size; (void)out_size;
    const int*   x     = (const int*)  d_in[0];
    const float* emb   = (const float*)d_in[1];
    const float* W_ih  = (const float*)d_in[2];
    const float* W_hh  = (const float*)d_in[3];
    const float* b_ih  = (const float*)d_in[4];
    const float* b_hh  = (const float*)d_in[5];
    const float* W_cls = (const float*)d_in[6];
    const float* b_cls = (const float*)d_in[7];
    float* out = (float*)d_out;

    const int lds_bytes = NV * 32 * 4;  // 128000 <= 163840 (gfx950 opt-in)
    hipFuncSetAttribute((const void*)lstm_fused,
                        hipFuncAttributeMaxDynamicSharedMemorySize, lds_bytes);

    lstm_fused<<<dim3(256), dim3(128), lds_bytes, stream>>>(
        x, emb, W_ih, W_hh, b_ih, b_hh, W_cls, b_cls, out);
}